// Round 3
// baseline (1255.746 us; speedup 1.0000x reference)
//
#include <hip/hip_runtime.h>

#define LN_EPS 1e-5f

typedef __bf16 bf16x8 __attribute__((ext_vector_type(8)));
typedef unsigned short ushort8v __attribute__((ext_vector_type(8)));
typedef float f32x4 __attribute__((ext_vector_type(4)));

__device__ __forceinline__ float bf16_to_f(unsigned short u) {
    unsigned int x = ((unsigned int)u) << 16;
    return __builtin_bit_cast(float, x);
}
__device__ __forceinline__ unsigned short f_to_bf16(float f) {
    unsigned int u = __builtin_bit_cast(unsigned int, f);
    u += 0x7FFFu + ((u >> 16) & 1u);   // round-to-nearest-even
    return (unsigned short)(u >> 16);
}
__device__ __forceinline__ int idx_at(const int* base, int i, int is64) {
    return is64 ? base[(long long)i << 1] : base[i];   // int64 LE: low word holds value
}

// dtype-polymorphic accessors ------------------------------------------------
template<int BF16>
__device__ __forceinline__ bf16x8 load_frag(const void* base, size_t off) {
    if (BF16) {
        return *(const bf16x8*)((const unsigned short*)base + off);
    } else {
        const float* p = (const float*)base + off;
        f32x4 a = *(const f32x4*)p;
        f32x4 b = *(const f32x4*)(p + 4);
        ushort8v u;
        u[0] = f_to_bf16(a[0]); u[1] = f_to_bf16(a[1]);
        u[2] = f_to_bf16(a[2]); u[3] = f_to_bf16(a[3]);
        u[4] = f_to_bf16(b[0]); u[5] = f_to_bf16(b[1]);
        u[6] = f_to_bf16(b[2]); u[7] = f_to_bf16(b[3]);
        return __builtin_bit_cast(bf16x8, u);
    }
}
template<int BF16>
__device__ __forceinline__ float load_sc(const void* base, size_t i) {
    return BF16 ? bf16_to_f(((const unsigned short*)base)[i]) : ((const float*)base)[i];
}
template<int BF16>
__device__ __forceinline__ void store_out(void* out, size_t i, float v) {
    if (BF16) ((unsigned short*)out)[i] = f_to_bf16(v);
    else      ((float*)out)[i] = v;
}

// ---------------------------------------------------------------------------
// flags[0] = edge_index is int64 (1) or int32 (0)
// flags[1] = float buffers are bf16 (1) or fp32 (0)
// Detection: even-indexed ushorts of x. True-bf16 N(0,1) data -> constrained
// exponent field; fp32 data -> those are uniform low-mantissa words.
// ---------------------------------------------------------------------------
__global__ void detect_kernel(const unsigned short* __restrict__ xu,
                              const unsigned int* __restrict__ ei,
                              int N, int* __restrict__ flags)
{
    if (threadIdx.x != 0 || blockIdx.x != 0) return;
    int inrange = 0;
    for (int i = 0; i < 64; ++i) {
        unsigned short u = xu[2 * i];
        int e = (u >> 7) & 0xFF;
        if (e >= 0x60 && e <= 0x8A) inrange++;
    }
    int isbf16 = (inrange >= 48) ? 1 : 0;

    int is64 = 1;
    for (int i = 0; i < 64; ++i) {
        unsigned int lo = ei[2 * i], hi = ei[2 * i + 1];
        if (hi != 0u || lo >= (unsigned int)N) { is64 = 0; break; }
    }
    flags[0] = is64;
    flags[1] = isbf16;
}

// ---------------------------------------------------------------------------
__global__ __launch_bounds__(256) void zero_kernel(float* __restrict__ p, int n4)
{
    int i = blockIdx.x * 256 + threadIdx.x;
    if (i < n4) {
        f32x4 z = {0.f, 0.f, 0.f, 0.f};
        ((f32x4*)p)[i] = z;
    }
}

// ---------------------------------------------------------------------------
// W (256x128 k-major) -> bf16 W^T (128x256 n-major) for contiguous B-fragments
// ---------------------------------------------------------------------------
template<int BF16>
__global__ __launch_bounds__(256) void prep_transpose(
    const void* __restrict__ Wm, const void* __restrict__ Wu,
    unsigned short* __restrict__ WmT, unsigned short* __restrict__ WuT,
    const int* __restrict__ flags)
{
    if (flags[1] != BF16) return;
    int idx = blockIdx.x * 256 + threadIdx.x;   // 0 .. 32767
    int k = idx >> 7;
    int n = idx & 127;
    unsigned short wm, wu;
    if (BF16) {
        wm = ((const unsigned short*)Wm)[idx];
        wu = ((const unsigned short*)Wu)[idx];
    } else {
        wm = f_to_bf16(((const float*)Wm)[idx]);
        wu = f_to_bf16(((const float*)Wu)[idx]);
    }
    WmT[n * 256 + k] = wm;
    WuT[n * 256 + k] = wu;
}

// ---------------------------------------------------------------------------
// Edge kernel: 128 edges / block, 4 waves; wave w owns cols [w*32, w*32+32).
// msg = relu([x[src]|edge_attr] @ W_msg + b_msg) -> atomic scatter to sumbuf[dst].
// MFMA 16x16x32 bf16: A[m=lane&15][k=quad*8+j], B^T[n=lane&15][k=quad*8+j],
// C/D: row = quad*4+reg, col = lane&15.
// ---------------------------------------------------------------------------
template<int BF16>
__global__ __launch_bounds__(256) void edge_kernel(
    const void* __restrict__ x, const int* __restrict__ eidx,
    const void* __restrict__ ea, const unsigned short* __restrict__ WmT,
    const void* __restrict__ b_msg,
    float* __restrict__ sumbuf, float* __restrict__ counts,
    const int* __restrict__ flags, int E)
{
    if (flags[1] != BF16) return;
    const int is64 = flags[0];
    const int* srcp = eidx;
    const int* dstp = eidx + (is64 ? 2 * E : E);

    const int ebase = blockIdx.x * 128;
    const int tid  = threadIdx.x;
    const int w    = tid >> 6;
    const int l    = tid & 63;
    const int m    = l & 15;
    const int quad = l >> 4;

    if (tid < 128 && (ebase + tid) < E) {
        atomicAdd(&counts[idx_at(dstp, ebase + tid, is64)], 1.0f);
    }

    bf16x8 bfrag[2][8];
#pragma unroll
    for (int nt = 0; nt < 2; ++nt) {
        const unsigned short* p = WmT + (w * 32 + nt * 16 + m) * 256 + quad * 8;
#pragma unroll
        for (int kk = 0; kk < 8; ++kk)
            bfrag[nt][kk] = *(const bf16x8*)(p + kk * 32);
    }
    const float bias0 = load_sc<BF16>(b_msg, w * 32 + m);
    const float bias1 = load_sc<BF16>(b_msg, w * 32 + 16 + m);

    for (int mt = 0; mt < 8; ++mt) {
        int e_a = ebase + mt * 16 + m;
        if (e_a >= E) e_a = E - 1;
        const int sa = idx_at(srcp, e_a, is64);
        const size_t xoff = (size_t)sa  * 128 + quad * 8;
        const size_t eoff = (size_t)e_a * 128 + quad * 8;

        f32x4 acc0 = {0.f, 0.f, 0.f, 0.f};
        f32x4 acc1 = {0.f, 0.f, 0.f, 0.f};
#pragma unroll
        for (int kk = 0; kk < 4; ++kk) {
            bf16x8 af = load_frag<BF16>(x, xoff + kk * 32);
            acc0 = __builtin_amdgcn_mfma_f32_16x16x32_bf16(af, bfrag[0][kk], acc0, 0, 0, 0);
            acc1 = __builtin_amdgcn_mfma_f32_16x16x32_bf16(af, bfrag[1][kk], acc1, 0, 0, 0);
        }
#pragma unroll
        for (int kk = 0; kk < 4; ++kk) {
            bf16x8 af = load_frag<BF16>(ea, eoff + kk * 32);
            acc0 = __builtin_amdgcn_mfma_f32_16x16x32_bf16(af, bfrag[0][kk + 4], acc0, 0, 0, 0);
            acc1 = __builtin_amdgcn_mfma_f32_16x16x32_bf16(af, bfrag[1][kk + 4], acc1, 0, 0, 0);
        }

#pragma unroll
        for (int i = 0; i < 4; ++i) {
            const int e = ebase + mt * 16 + quad * 4 + i;
            if (e < E) {
                const int dn = idx_at(dstp, e, is64);
                float v0 = acc0[i] + bias0; v0 = v0 > 0.f ? v0 : 0.f;
                float v1 = acc1[i] + bias1; v1 = v1 > 0.f ? v1 : 0.f;
                atomicAdd(&sumbuf[(size_t)dn * 128 + w * 32 + m], v0);
                atomicAdd(&sumbuf[(size_t)dn * 128 + w * 32 + 16 + m], v1);
            }
        }
    }
}

// ---------------------------------------------------------------------------
// Node kernel: 64 nodes / block, 4 waves; wave w owns cols [w*32, w*32+32).
// h = [x | mean_msg] @ W_upd + b_upd; LayerNorm; out = relu(h_ln + x).
// ---------------------------------------------------------------------------
template<int BF16>
__global__ __launch_bounds__(256) void node_kernel(
    const void* __restrict__ x,
    const float* __restrict__ sumbuf, const float* __restrict__ counts,
    const unsigned short* __restrict__ WuT, const void* __restrict__ b_upd,
    const void* __restrict__ gamma_, const void* __restrict__ beta_,
    void* __restrict__ out, const int* __restrict__ flags, int N)
{
    if (flags[1] != BF16) return;

    __shared__ float redS[4][64];
    __shared__ float redQ[4][64];
    __shared__ float muS[64];
    __shared__ float rsS[64];

    const int rbase = blockIdx.x * 64;
    const int tid  = threadIdx.x;
    const int w    = tid >> 6;
    const int l    = tid & 63;
    const int m    = l & 15;
    const int quad = l >> 4;

    bf16x8 bfrag[2][8];
#pragma unroll
    for (int nt = 0; nt < 2; ++nt) {
        const unsigned short* p = WuT + (w * 32 + nt * 16 + m) * 256 + quad * 8;
#pragma unroll
        for (int kk = 0; kk < 8; ++kk)
            bfrag[nt][kk] = *(const bf16x8*)(p + kk * 32);
    }
    const float bias0 = load_sc<BF16>(b_upd, w * 32 + m);
    const float bias1 = load_sc<BF16>(b_upd, w * 32 + 16 + m);

    f32x4 acc[4][2];

    for (int mt = 0; mt < 4; ++mt) {
        int r = rbase + mt * 16 + m;
        int rc = r < N ? r : N - 1;
        const size_t xoff = (size_t)rc * 128 + quad * 8;
        const float* srow = sumbuf + (size_t)rc * 128 + quad * 8;
        const float rcp = 1.0f / fmaxf(counts[rc], 1.0f);

        f32x4 a0 = {0.f, 0.f, 0.f, 0.f};
        f32x4 a1 = {0.f, 0.f, 0.f, 0.f};
#pragma unroll
        for (int kk = 0; kk < 4; ++kk) {
            bf16x8 af = load_frag<BF16>(x, xoff + kk * 32);
            a0 = __builtin_amdgcn_mfma_f32_16x16x32_bf16(af, bfrag[0][kk], a0, 0, 0, 0);
            a1 = __builtin_amdgcn_mfma_f32_16x16x32_bf16(af, bfrag[1][kk], a1, 0, 0, 0);
        }
#pragma unroll
        for (int kk = 0; kk < 4; ++kk) {
            const float* sp = srow + kk * 32;
            ushort8v uu;
#pragma unroll
            for (int j = 0; j < 8; ++j) uu[j] = f_to_bf16(sp[j] * rcp);
            bf16x8 av = __builtin_bit_cast(bf16x8, uu);
            a0 = __builtin_amdgcn_mfma_f32_16x16x32_bf16(av, bfrag[0][kk + 4], a0, 0, 0, 0);
            a1 = __builtin_amdgcn_mfma_f32_16x16x32_bf16(av, bfrag[1][kk + 4], a1, 0, 0, 0);
        }

        float ps[4], qs[4];
#pragma unroll
        for (int i = 0; i < 4; ++i) {
            a0[i] += bias0;
            a1[i] += bias1;
            ps[i] = a0[i] + a1[i];
            qs[i] = a0[i] * a0[i] + a1[i] * a1[i];
        }
        acc[mt][0] = a0;
        acc[mt][1] = a1;

#pragma unroll
        for (int s = 1; s < 16; s <<= 1) {
#pragma unroll
            for (int i = 0; i < 4; ++i) {
                ps[i] += __shfl_xor(ps[i], s, 64);
                qs[i] += __shfl_xor(qs[i], s, 64);
            }
        }
        if (m == 0) {
#pragma unroll
            for (int i = 0; i < 4; ++i) {
                redS[w][mt * 16 + quad * 4 + i] = ps[i];
                redQ[w][mt * 16 + quad * 4 + i] = qs[i];
            }
        }
    }
    __syncthreads();

    if (tid < 64) {
        float s = redS[0][tid] + redS[1][tid] + redS[2][tid] + redS[3][tid];
        float q = redQ[0][tid] + redQ[1][tid] + redQ[2][tid] + redQ[3][tid];
        float mu = s * (1.0f / 128.0f);
        float var = q * (1.0f / 128.0f) - mu * mu;
        muS[tid] = mu;
        rsS[tid] = rsqrtf(var + LN_EPS);
    }
    __syncthreads();

    const float g0  = load_sc<BF16>(gamma_, w * 32 + m);
    const float be0 = load_sc<BF16>(beta_,  w * 32 + m);
    const float g1  = load_sc<BF16>(gamma_, w * 32 + 16 + m);
    const float be1 = load_sc<BF16>(beta_,  w * 32 + 16 + m);

    for (int mt = 0; mt < 4; ++mt) {
#pragma unroll
        for (int i = 0; i < 4; ++i) {
            const int ridx = mt * 16 + quad * 4 + i;
            const int r = rbase + ridx;
            if (r < N) {
                const float mu = muS[ridx];
                const float rs = rsS[ridx];
                const size_t c0 = (size_t)r * 128 + w * 32 + m;
                const size_t c1 = c0 + 16;
                float v0 = (acc[mt][0][i] - mu) * rs * g0 + be0 + load_sc<BF16>(x, c0);
                float v1 = (acc[mt][1][i] - mu) * rs * g1 + be1 + load_sc<BF16>(x, c1);
                store_out<BF16>(out, c0, v0 > 0.f ? v0 : 0.f);
                store_out<BF16>(out, c1, v1 > 0.f ? v1 : 0.f);
            }
        }
    }
}

// ---------------------------------------------------------------------------
extern "C" void kernel_launch(void* const* d_in, const int* in_sizes, int n_in,
                              void* d_out, int out_size, void* d_ws, size_t ws_size,
                              hipStream_t stream)
{
    const void* x  = d_in[0];
    const int*  ei = (const int*)d_in[1];
    const void* ea = d_in[2];
    const void* Wm = d_in[3];
    const void* bm = d_in[4];
    const void* Wu = d_in[5];
    const void* bu = d_in[6];
    const void* gm = d_in[7];
    const void* bt = d_in[8];

    const int N = in_sizes[0] / 128;
    const int E = in_sizes[2] / 128;

    // ws layout: [0) flags int[4] | [16) sumbuf N*128 f32 | counts N f32 | WmT | WuT
    char* ws = (char*)d_ws;
    int*   flags  = (int*)ws;
    float* sumbuf = (float*)(ws + 16);
    float* counts = (float*)(ws + 16 + (size_t)N * 512);
    unsigned short* WmT = (unsigned short*)(ws + 16 + (size_t)N * 512 + (size_t)N * 4);
    unsigned short* WuT = WmT + 256 * 128;

    detect_kernel<<<1, 64, 0, stream>>>((const unsigned short*)x,
                                        (const unsigned int*)ei, N, flags);

    const int n4 = (N * 129 + 3) / 4;
    zero_kernel<<<(n4 + 255) / 256, 256, 0, stream>>>(sumbuf, n4);

    prep_transpose<0><<<128, 256, 0, stream>>>(Wm, Wu, WmT, WuT, flags);
    prep_transpose<1><<<128, 256, 0, stream>>>(Wm, Wu, WmT, WuT, flags);

    const int eblocks = (E + 127) / 128;
    edge_kernel<0><<<eblocks, 256, 0, stream>>>(x, ei, ea, WmT, bm, sumbuf, counts, flags, E);
    edge_kernel<1><<<eblocks, 256, 0, stream>>>(x, ei, ea, WmT, bm, sumbuf, counts, flags, E);

    const int nblocks = (N + 63) / 64;
    node_kernel<0><<<nblocks, 256, 0, stream>>>(x, sumbuf, counts, WuT, bu, gm, bt, d_out, flags, N);
    node_kernel<1><<<nblocks, 256, 0, stream>>>(x, sumbuf, counts, WuT, bu, gm, bt, d_out, flags, N);
}